// Round 3
// baseline (199.743 us; speedup 1.0000x reference)
//
#include <hip/hip_runtime.h>

#define B_  2
#define TQ  1024
#define TV  1024
#define DD  512
#define UU  128

#define KS  4            // k-splits for scores kernel
#define KR  (TV/KS)      // 256 k per block

#define CM  32
#define CN  64
#define CKT 64

// ---------------- prep: scale2[u] = -2*scale[u] ----------------
__global__ void prep_scale(const float* __restrict__ scale, float* __restrict__ scale2){
    int u = threadIdx.x;
    if (u < UU) scale2[u] = -2.0f * scale[u];
}

// ---------------- projections: q2 = C*query@W1, k2 = C*value@W2 (C = 2*log2(e)) ----
__global__ __launch_bounds__(256)
void proj_kernel(const float* __restrict__ query, const float* __restrict__ value,
                 const float* __restrict__ W1,    const float* __restrict__ W2,
                 float* __restrict__ q2, float* __restrict__ k2){
    const float TWO_LOG2E = 2.8853900817779268f;
    const float* X = blockIdx.z ? value : query;
    const float* W = blockIdx.z ? W2    : W1;
    float* out     = blockIdx.z ? k2    : q2;

    const int u    = threadIdx.x & 127;
    const int half = threadIdx.x >> 7;
    const int b    = blockIdx.y;
    const int t0   = blockIdx.x * 8 + half * 4;
    const float* x = X + ((size_t)b * TQ + t0) * DD;

    float acc0 = 0.f, acc1 = 0.f, acc2 = 0.f, acc3 = 0.f;
    for (int d = 0; d < DD; d += 4){
        float w0 = W[(d+0)*UU + u];
        float w1 = W[(d+1)*UU + u];
        float w2 = W[(d+2)*UU + u];
        float w3 = W[(d+3)*UU + u];
        float4 x0 = *reinterpret_cast<const float4*>(x + 0*DD + d);
        float4 x1 = *reinterpret_cast<const float4*>(x + 1*DD + d);
        float4 x2 = *reinterpret_cast<const float4*>(x + 2*DD + d);
        float4 x3 = *reinterpret_cast<const float4*>(x + 3*DD + d);
        acc0 = fmaf(x0.x,w0,acc0); acc0 = fmaf(x0.y,w1,acc0); acc0 = fmaf(x0.z,w2,acc0); acc0 = fmaf(x0.w,w3,acc0);
        acc1 = fmaf(x1.x,w0,acc1); acc1 = fmaf(x1.y,w1,acc1); acc1 = fmaf(x1.z,w2,acc1); acc1 = fmaf(x1.w,w3,acc1);
        acc2 = fmaf(x2.x,w0,acc2); acc2 = fmaf(x2.y,w1,acc2); acc2 = fmaf(x2.z,w2,acc2); acc2 = fmaf(x2.w,w3,acc2);
        acc3 = fmaf(x3.x,w0,acc3); acc3 = fmaf(x3.y,w1,acc3); acc3 = fmaf(x3.z,w2,acc3); acc3 = fmaf(x3.w,w3,acc3);
    }
    size_t o = ((size_t)b * TQ + t0) * UU + u;
    out[o + 0*UU] = TWO_LOG2E * acc0;
    out[o + 1*UU] = TWO_LOG2E * acc1;
    out[o + 2*UU] = TWO_LOG2E * acc2;
    out[o + 3*UU] = TWO_LOG2E * acc3;
}

// ---------------- raw scores ----------------
// scores[b,q,k] = sum_u scale2[u] * rcp(1 + exp2(q2[b,q,u] + k2[b,k,u]))  (+const, cancels)
// block = 2 waves, owns 4 q-rows x 256 k; wave w covers u-slice [w*64, w*64+64)
// k2 read straight from L2 (1 MB resident), 4-row register reuse, 1-deep prefetch
__global__ __launch_bounds__(128)
void scores_kernel(const float* __restrict__ q2, const float* __restrict__ k2,
                   const float* __restrict__ scale2, float* __restrict__ scores){
    __shared__ float qs[4][UU];
    __shared__ float sc[UU];
    __shared__ float red[2][4][4][64];

    const int b    = blockIdx.z;
    const int q0   = blockIdx.x * 4;
    const int k0   = blockIdx.y * KR;
    const int tid  = threadIdx.x;
    const int w    = tid >> 6, lane = tid & 63;

    for (int i = tid; i < 4*UU; i += 128)
        qs[i >> 7][i & 127] = q2[((size_t)b * TQ + q0 + (i >> 7)) * UU + (i & 127)];
    if (tid < UU) sc[tid] = scale2[tid];
    __syncthreads();

    const float4* k2v = reinterpret_cast<const float4*>(k2 + (size_t)b * TV * UU);
    const float4* qs4 = reinterpret_cast<const float4*>(&qs[0][0]);   // row r: qs4[r*32 + j]
    const float4* sc4 = reinterpret_cast<const float4*>(&sc[0]);

    int kidx[4];
    #pragma unroll
    for (int i = 0; i < 4; ++i) kidx[i] = (k0 + i*64 + lane) * 32;    // float4 units

    const int j0 = w * 16;
    float acc[4][4] = {};
    float4 kv[4], kvn[4];
    #pragma unroll
    for (int i = 0; i < 4; ++i) kv[i] = k2v[kidx[i] + j0];

    #pragma unroll
    for (int jj = 0; jj < 16; ++jj){
        const int j = j0 + jj;
        if (jj != 15){
            #pragma unroll
            for (int i = 0; i < 4; ++i) kvn[i] = k2v[kidx[i] + j + 1];
        }
        float4 s4 = sc4[j];
        #pragma unroll
        for (int r = 0; r < 4; ++r){
            float4 q4 = qs4[r*32 + j];
            #pragma unroll
            for (int i = 0; i < 4; ++i){
                acc[r][i] = fmaf(s4.x, __builtin_amdgcn_rcpf(1.0f + __builtin_amdgcn_exp2f(q4.x + kv[i].x)), acc[r][i]);
                acc[r][i] = fmaf(s4.y, __builtin_amdgcn_rcpf(1.0f + __builtin_amdgcn_exp2f(q4.y + kv[i].y)), acc[r][i]);
                acc[r][i] = fmaf(s4.z, __builtin_amdgcn_rcpf(1.0f + __builtin_amdgcn_exp2f(q4.z + kv[i].z)), acc[r][i]);
                acc[r][i] = fmaf(s4.w, __builtin_amdgcn_rcpf(1.0f + __builtin_amdgcn_exp2f(q4.w + kv[i].w)), acc[r][i]);
            }
        }
        #pragma unroll
        for (int i = 0; i < 4; ++i) kv[i] = kvn[i];
    }

    // combine the two u-halves
    #pragma unroll
    for (int r = 0; r < 4; ++r)
        #pragma unroll
        for (int i = 0; i < 4; ++i) red[w][r][i][lane] = acc[r][i];
    __syncthreads();

    #pragma unroll
    for (int rr = 0; rr < 2; ++rr){
        int r = 2*w + rr;
        #pragma unroll
        for (int i = 0; i < 4; ++i){
            float v = red[0][r][i][lane] + red[1][r][i][lane];
            scores[((size_t)b * TQ + q0 + r) * TV + k0 + i*64 + lane] = v;
        }
    }
}

// ---------------- softmax over k (one wave per q-row) ----------------
__global__ __launch_bounds__(256)
void softmax_kernel(const float* __restrict__ scores, float* __restrict__ attn){
    const float LOG2E = 1.4426950408889634f;
    const int b = blockIdx.y, q = blockIdx.x * 4 + (threadIdx.x >> 6);
    const int lane = threadIdx.x & 63;
    const float* srow = scores + ((size_t)b * TQ + q) * TV;

    float s[16];
    #pragma unroll
    for (int t = 0; t < 16; ++t) s[t] = srow[t*64 + lane];

    float m = s[0];
    #pragma unroll
    for (int t = 1; t < 16; ++t) m = fmaxf(m, s[t]);
    #pragma unroll
    for (int off = 32; off >= 1; off >>= 1) m = fmaxf(m, __shfl_xor(m, off, 64));
    float sum = 0.f;
    #pragma unroll
    for (int t = 0; t < 16; ++t){ s[t] = __builtin_amdgcn_exp2f((s[t] - m) * LOG2E); sum += s[t]; }
    #pragma unroll
    for (int off = 32; off >= 1; off >>= 1) sum += __shfl_xor(sum, off, 64);
    float inv = 1.0f / sum;

    float* arow = attn + ((size_t)b * TQ + q) * TV;
    #pragma unroll
    for (int t = 0; t < 16; ++t) arow[t*64 + lane] = s[t] * inv;
}

// ---------------- context = attn @ value (all fp32) ----------------
__global__ __launch_bounds__(256)
void ctx_kernel(const float* __restrict__ attn, const float* __restrict__ value,
                float* __restrict__ ctx){
    __shared__ float As[CM][CKT + 4];
    __shared__ float Vs[CKT][CN];

    const int b  = blockIdx.z;
    const int m0 = blockIdx.x * CM;
    const int n0 = blockIdx.y * CN;
    const int tid = threadIdx.x;
    const int tx = tid & 15, ty = tid >> 4;

    const float* abase = attn + ((size_t)b * TQ + m0) * TV;
    const float* vbase = value + (size_t)b * TV * DD;

    float acc[2][4] = {};
    for (int kt = 0; kt < TV; kt += CKT){
        __syncthreads();
        #pragma unroll
        for (int i = 0; i < 2; ++i){
            int id = tid + 256*i;
            int row = id >> 4, c4 = id & 15;
            *reinterpret_cast<float4*>(&As[row][c4*4]) =
                *reinterpret_cast<const float4*>(abase + (size_t)row * TV + kt + c4*4);
        }
        #pragma unroll
        for (int i = 0; i < 4; ++i){
            int id = tid + 256*i;
            int row = id >> 4, c4 = id & 15;
            *reinterpret_cast<float4*>(&Vs[row][c4*4]) =
                *reinterpret_cast<const float4*>(vbase + (size_t)(kt + row) * DD + n0 + c4*4);
        }
        __syncthreads();
        #pragma unroll
        for (int k = 0; k < CKT; ++k){
            float a0 = As[ty*2+0][k];
            float a1 = As[ty*2+1][k];
            float4 b4 = *reinterpret_cast<const float4*>(&Vs[k][tx*4]);
            acc[0][0] = fmaf(a0, b4.x, acc[0][0]);
            acc[0][1] = fmaf(a0, b4.y, acc[0][1]);
            acc[0][2] = fmaf(a0, b4.z, acc[0][2]);
            acc[0][3] = fmaf(a0, b4.w, acc[0][3]);
            acc[1][0] = fmaf(a1, b4.x, acc[1][0]);
            acc[1][1] = fmaf(a1, b4.y, acc[1][1]);
            acc[1][2] = fmaf(a1, b4.z, acc[1][2]);
            acc[1][3] = fmaf(a1, b4.w, acc[1][3]);
        }
    }
    #pragma unroll
    for (int i = 0; i < 2; ++i){
        float4 o;
        o.x = acc[i][0]; o.y = acc[i][1]; o.z = acc[i][2]; o.w = acc[i][3];
        *reinterpret_cast<float4*>(ctx + ((size_t)b * TQ + m0 + ty*2 + i) * DD + n0 + tx*4) = o;
    }
}

extern "C" void kernel_launch(void* const* d_in, const int* in_sizes, int n_in,
                              void* d_out, int out_size, void* d_ws, size_t ws_size,
                              hipStream_t stream){
    const float* query = (const float*)d_in[0];
    const float* value = (const float*)d_in[1];
    const float* W1    = (const float*)d_in[2];
    const float* W2    = (const float*)d_in[3];
    const float* scale = (const float*)d_in[4];

    float* q2     = (float*)d_ws;                          // 1 MB
    float* k2     = q2 + (size_t)B_ * TQ * UU;             // 1 MB
    float* scale2 = k2 + (size_t)B_ * TV * UU;             // 512 B
    float* scores = scale2 + 256;                          // 8 MB raw scores

    float* out  = (float*)d_out;
    float* ctx  = out;                                     // [B][TQ][DD]
    float* attn = out + (size_t)B_ * TQ * DD;              // [B][TQ][TV]

    prep_scale<<<1, 128, 0, stream>>>(scale, scale2);
    proj_kernel<<<dim3(TQ/8, B_, 2), 256, 0, stream>>>(query, value, W1, W2, q2, k2);
    scores_kernel<<<dim3(TQ/4, KS, B_), 128, 0, stream>>>(q2, k2, scale2, scores);
    softmax_kernel<<<dim3(TQ/4, B_), 256, 0, stream>>>(scores, attn);
    ctx_kernel<<<dim3(TQ/CM, DD/CN, B_), 256, 0, stream>>>(attn, value, ctx);
}

// Round 4
// 149.201 us; speedup vs baseline: 1.3388x; 1.3388x over previous
//
#include <hip/hip_runtime.h>

#define B_  2
#define TQ  1024
#define TV  1024
#define DD  512
#define UU  128

#define QB  4            // q-rows per block (scores)
#define KS  2            // k-splits (scores)
#define KR  (TV/KS)      // 512 k per block

#define CM  32
#define CN  64
#define CKT 64

// ---------------- projections: q2 = C*query@W1, k2 = C*value@W2 (C = 2*log2(e)) ----
__global__ __launch_bounds__(256)
void proj_kernel(const float* __restrict__ query, const float* __restrict__ value,
                 const float* __restrict__ W1,    const float* __restrict__ W2,
                 float* __restrict__ q2, float* __restrict__ k2){
    const float TWO_LOG2E = 2.8853900817779268f;
    const float* X = blockIdx.z ? value : query;
    const float* W = blockIdx.z ? W2    : W1;
    float* out     = blockIdx.z ? k2    : q2;

    const int u    = threadIdx.x & 127;
    const int half = threadIdx.x >> 7;
    const int b    = blockIdx.y;
    const int t0   = blockIdx.x * 8 + half * 4;
    const float* x = X + ((size_t)b * TQ + t0) * DD;

    float acc0 = 0.f, acc1 = 0.f, acc2 = 0.f, acc3 = 0.f;
    for (int d = 0; d < DD; d += 4){
        float w0 = W[(d+0)*UU + u];
        float w1 = W[(d+1)*UU + u];
        float w2 = W[(d+2)*UU + u];
        float w3 = W[(d+3)*UU + u];
        float4 x0 = *reinterpret_cast<const float4*>(x + 0*DD + d);
        float4 x1 = *reinterpret_cast<const float4*>(x + 1*DD + d);
        float4 x2 = *reinterpret_cast<const float4*>(x + 2*DD + d);
        float4 x3 = *reinterpret_cast<const float4*>(x + 3*DD + d);
        acc0 = fmaf(x0.x,w0,acc0); acc0 = fmaf(x0.y,w1,acc0); acc0 = fmaf(x0.z,w2,acc0); acc0 = fmaf(x0.w,w3,acc0);
        acc1 = fmaf(x1.x,w0,acc1); acc1 = fmaf(x1.y,w1,acc1); acc1 = fmaf(x1.z,w2,acc1); acc1 = fmaf(x1.w,w3,acc1);
        acc2 = fmaf(x2.x,w0,acc2); acc2 = fmaf(x2.y,w1,acc2); acc2 = fmaf(x2.z,w2,acc2); acc2 = fmaf(x2.w,w3,acc2);
        acc3 = fmaf(x3.x,w0,acc3); acc3 = fmaf(x3.y,w1,acc3); acc3 = fmaf(x3.z,w2,acc3); acc3 = fmaf(x3.w,w3,acc3);
    }
    size_t o = ((size_t)b * TQ + t0) * UU + u;
    out[o + 0*UU] = TWO_LOG2E * acc0;
    out[o + 1*UU] = TWO_LOG2E * acc1;
    out[o + 2*UU] = TWO_LOG2E * acc2;
    out[o + 3*UU] = TWO_LOG2E * acc3;
}

// ---------------- raw scores ----------------
// scores[b,q,k] = sum_u (-2*scale[u]) * rcp(1 + exp2(q2[b,q,u] + k2[b,k,u]))  (+const, cancels)
// block = 4 waves; wave w owns k-range [k0+w*128, +128) (2 k per lane), computes all 4 q-rows.
// k2 from global (L2-resident), q/scale broadcast from LDS. acc[4][2] only -> low VGPR.
__global__ __launch_bounds__(256, 4)
void scores_kernel(const float* __restrict__ q2, const float* __restrict__ k2,
                   const float* __restrict__ scale, float* __restrict__ scores){
    __shared__ float qs[QB][UU];
    __shared__ float sc[UU];

    const int b   = blockIdx.z;
    const int q0  = blockIdx.x * QB;
    const int k0  = blockIdx.y * KR;
    const int tid = threadIdx.x;
    const int w   = tid >> 6, lane = tid & 63;

    #pragma unroll
    for (int i = 0; i < 2; ++i){
        int id = tid + 256*i;                   // 0..511
        qs[id >> 7][id & 127] = q2[((size_t)b * TQ + q0 + (id >> 7)) * UU + (id & 127)];
    }
    if (tid < UU) sc[tid] = -2.0f * scale[tid];
    __syncthreads();

    const float4* k2v = reinterpret_cast<const float4*>(k2 + (size_t)b * TV * UU);
    const float4* qs4 = reinterpret_cast<const float4*>(&qs[0][0]);   // row r: qs4[r*32 + j]
    const float4* sc4 = reinterpret_cast<const float4*>(&sc[0]);

    const int kA = k0 + w*128 + lane;           // first k this lane owns
    const int kB = kA + 64;                     // second
    const size_t iA = (size_t)kA * 32;          // float4 index base
    const size_t iB = (size_t)kB * 32;

    float acc[QB][2] = {};
    float4 kva = k2v[iA];
    float4 kvb = k2v[iB];

    for (int j = 0; j < 32; ++j){
        float4 nka, nkb;
        if (j != 31){ nka = k2v[iA + j + 1]; nkb = k2v[iB + j + 1]; }
        float4 s4 = sc4[j];
        #pragma unroll
        for (int r = 0; r < QB; ++r){
            float4 q4 = qs4[r*32 + j];
            acc[r][0] = fmaf(s4.x, __builtin_amdgcn_rcpf(1.0f + __builtin_amdgcn_exp2f(q4.x + kva.x)), acc[r][0]);
            acc[r][0] = fmaf(s4.y, __builtin_amdgcn_rcpf(1.0f + __builtin_amdgcn_exp2f(q4.y + kva.y)), acc[r][0]);
            acc[r][0] = fmaf(s4.z, __builtin_amdgcn_rcpf(1.0f + __builtin_amdgcn_exp2f(q4.z + kva.z)), acc[r][0]);
            acc[r][0] = fmaf(s4.w, __builtin_amdgcn_rcpf(1.0f + __builtin_amdgcn_exp2f(q4.w + kva.w)), acc[r][0]);
            acc[r][1] = fmaf(s4.x, __builtin_amdgcn_rcpf(1.0f + __builtin_amdgcn_exp2f(q4.x + kvb.x)), acc[r][1]);
            acc[r][1] = fmaf(s4.y, __builtin_amdgcn_rcpf(1.0f + __builtin_amdgcn_exp2f(q4.y + kvb.y)), acc[r][1]);
            acc[r][1] = fmaf(s4.z, __builtin_amdgcn_rcpf(1.0f + __builtin_amdgcn_exp2f(q4.z + kvb.z)), acc[r][1]);
            acc[r][1] = fmaf(s4.w, __builtin_amdgcn_rcpf(1.0f + __builtin_amdgcn_exp2f(q4.w + kvb.w)), acc[r][1]);
        }
        kva = nka; kvb = nkb;
    }

    #pragma unroll
    for (int r = 0; r < QB; ++r){
        float* row = scores + ((size_t)b * TQ + q0 + r) * TV;
        row[kA] = acc[r][0];
        row[kB] = acc[r][1];
    }
}

// ---------------- softmax over k (one wave per q-row) ----------------
__global__ __launch_bounds__(256)
void softmax_kernel(const float* __restrict__ scores, float* __restrict__ attn){
    const float LOG2E = 1.4426950408889634f;
    const int b = blockIdx.y, q = blockIdx.x * 4 + (threadIdx.x >> 6);
    const int lane = threadIdx.x & 63;
    const float* srow = scores + ((size_t)b * TQ + q) * TV;

    float s[16];
    #pragma unroll
    for (int t = 0; t < 16; ++t) s[t] = srow[t*64 + lane];

    float m = s[0];
    #pragma unroll
    for (int t = 1; t < 16; ++t) m = fmaxf(m, s[t]);
    #pragma unroll
    for (int off = 32; off >= 1; off >>= 1) m = fmaxf(m, __shfl_xor(m, off, 64));
    float sum = 0.f;
    #pragma unroll
    for (int t = 0; t < 16; ++t){ s[t] = __builtin_amdgcn_exp2f((s[t] - m) * LOG2E); sum += s[t]; }
    #pragma unroll
    for (int off = 32; off >= 1; off >>= 1) sum += __shfl_xor(sum, off, 64);
    float inv = 1.0f / sum;

    float* arow = attn + ((size_t)b * TQ + q) * TV;
    #pragma unroll
    for (int t = 0; t < 16; ++t) arow[t*64 + lane] = s[t] * inv;
}

// ---------------- context = attn @ value (all fp32) ----------------
__global__ __launch_bounds__(256)
void ctx_kernel(const float* __restrict__ attn, const float* __restrict__ value,
                float* __restrict__ ctx){
    __shared__ float As[CM][CKT + 4];
    __shared__ float Vs[CKT][CN];

    const int b  = blockIdx.z;
    const int m0 = blockIdx.x * CM;
    const int n0 = blockIdx.y * CN;
    const int tid = threadIdx.x;
    const int tx = tid & 15, ty = tid >> 4;

    const float* abase = attn + ((size_t)b * TQ + m0) * TV;
    const float* vbase = value + (size_t)b * TV * DD;

    float acc[2][4] = {};
    for (int kt = 0; kt < TV; kt += CKT){
        __syncthreads();
        #pragma unroll
        for (int i = 0; i < 2; ++i){
            int id = tid + 256*i;
            int row = id >> 4, c4 = id & 15;
            *reinterpret_cast<float4*>(&As[row][c4*4]) =
                *reinterpret_cast<const float4*>(abase + (size_t)row * TV + kt + c4*4);
        }
        #pragma unroll
        for (int i = 0; i < 4; ++i){
            int id = tid + 256*i;
            int row = id >> 4, c4 = id & 15;
            *reinterpret_cast<float4*>(&Vs[row][c4*4]) =
                *reinterpret_cast<const float4*>(vbase + (size_t)(kt + row) * DD + n0 + c4*4);
        }
        __syncthreads();
        #pragma unroll
        for (int k = 0; k < CKT; ++k){
            float a0 = As[ty*2+0][k];
            float a1 = As[ty*2+1][k];
            float4 b4 = *reinterpret_cast<const float4*>(&Vs[k][tx*4]);
            acc[0][0] = fmaf(a0, b4.x, acc[0][0]);
            acc[0][1] = fmaf(a0, b4.y, acc[0][1]);
            acc[0][2] = fmaf(a0, b4.z, acc[0][2]);
            acc[0][3] = fmaf(a0, b4.w, acc[0][3]);
            acc[1][0] = fmaf(a1, b4.x, acc[1][0]);
            acc[1][1] = fmaf(a1, b4.y, acc[1][1]);
            acc[1][2] = fmaf(a1, b4.z, acc[1][2]);
            acc[1][3] = fmaf(a1, b4.w, acc[1][3]);
        }
    }
    #pragma unroll
    for (int i = 0; i < 2; ++i){
        float4 o;
        o.x = acc[i][0]; o.y = acc[i][1]; o.z = acc[i][2]; o.w = acc[i][3];
        *reinterpret_cast<float4*>(ctx + ((size_t)b * TQ + m0 + ty*2 + i) * DD + n0 + tx*4) = o;
    }
}

extern "C" void kernel_launch(void* const* d_in, const int* in_sizes, int n_in,
                              void* d_out, int out_size, void* d_ws, size_t ws_size,
                              hipStream_t stream){
    const float* query = (const float*)d_in[0];
    const float* value = (const float*)d_in[1];
    const float* W1    = (const float*)d_in[2];
    const float* W2    = (const float*)d_in[3];
    const float* scale = (const float*)d_in[4];

    float* q2     = (float*)d_ws;                          // 1 MB
    float* k2     = q2 + (size_t)B_ * TQ * UU;             // 1 MB
    float* scores = k2 + (size_t)B_ * TV * UU;             // 8 MB raw scores

    float* out  = (float*)d_out;
    float* ctx  = out;                                     // [B][TQ][DD]
    float* attn = out + (size_t)B_ * TQ * DD;              // [B][TQ][TV]

    proj_kernel<<<dim3(TQ/8, B_, 2), 256, 0, stream>>>(query, value, W1, W2, q2, k2);
    scores_kernel<<<dim3(TQ/QB, KS, B_), 256, 0, stream>>>(q2, k2, scale, scores);
    softmax_kernel<<<dim3(TQ/4, B_), 256, 0, stream>>>(scores, attn);
    ctx_kernel<<<dim3(TQ/CM, DD/CN, B_), 256, 0, stream>>>(attn, value, ctx);
}

// Round 5
// 148.672 us; speedup vs baseline: 1.3435x; 1.0036x over previous
//
#include <hip/hip_runtime.h>

#define B_  2
#define TQ  1024
#define TV  1024
#define DD  512
#define UU  128

#define QB  4            // q-rows per block (scores)
#define KS  4            // k-splits (scores)
#define KR  (TV/KS)      // 256 k per block

#define CM  32
#define CN  64
#define CKT 64

// ---------------- projections: q2 = C*query@W1, k2 = C*value@W2 (C = 2*log2(e)) ----
__global__ __launch_bounds__(256)
void proj_kernel(const float* __restrict__ query, const float* __restrict__ value,
                 const float* __restrict__ W1,    const float* __restrict__ W2,
                 float* __restrict__ q2, float* __restrict__ k2){
    const float TWO_LOG2E = 2.8853900817779268f;
    const float* X = blockIdx.z ? value : query;
    const float* W = blockIdx.z ? W2    : W1;
    float* out     = blockIdx.z ? k2    : q2;

    const int u    = threadIdx.x & 127;
    const int half = threadIdx.x >> 7;
    const int b    = blockIdx.y;
    const int t0   = blockIdx.x * 8 + half * 4;
    const float* x = X + ((size_t)b * TQ + t0) * DD;

    float acc0 = 0.f, acc1 = 0.f, acc2 = 0.f, acc3 = 0.f;
    for (int d = 0; d < DD; d += 4){
        float w0 = W[(d+0)*UU + u];
        float w1 = W[(d+1)*UU + u];
        float w2 = W[(d+2)*UU + u];
        float w3 = W[(d+3)*UU + u];
        float4 x0 = *reinterpret_cast<const float4*>(x + 0*DD + d);
        float4 x1 = *reinterpret_cast<const float4*>(x + 1*DD + d);
        float4 x2 = *reinterpret_cast<const float4*>(x + 2*DD + d);
        float4 x3 = *reinterpret_cast<const float4*>(x + 3*DD + d);
        acc0 = fmaf(x0.x,w0,acc0); acc0 = fmaf(x0.y,w1,acc0); acc0 = fmaf(x0.z,w2,acc0); acc0 = fmaf(x0.w,w3,acc0);
        acc1 = fmaf(x1.x,w0,acc1); acc1 = fmaf(x1.y,w1,acc1); acc1 = fmaf(x1.z,w2,acc1); acc1 = fmaf(x1.w,w3,acc1);
        acc2 = fmaf(x2.x,w0,acc2); acc2 = fmaf(x2.y,w1,acc2); acc2 = fmaf(x2.z,w2,acc2); acc2 = fmaf(x2.w,w3,acc2);
        acc3 = fmaf(x3.x,w0,acc3); acc3 = fmaf(x3.y,w1,acc3); acc3 = fmaf(x3.z,w2,acc3); acc3 = fmaf(x3.w,w3,acc3);
    }
    size_t o = ((size_t)b * TQ + t0) * UU + u;
    out[o + 0*UU] = TWO_LOG2E * acc0;
    out[o + 1*UU] = TWO_LOG2E * acc1;
    out[o + 2*UU] = TWO_LOG2E * acc2;
    out[o + 3*UU] = TWO_LOG2E * acc3;
}

// ---------------- raw scores ----------------
// scores[b,q,k] = sum_u (-2*scale[u]) * rcp(1 + exp2(q2[b,q,u] + k2[b,k,u]))  (+const, cancels)
// block = 4 waves; wave w owns 64 k (1 per lane), computes all 4 q-rows over full u.
// k2 from global (L2-resident), q/scale broadcast from LDS. acc[4] + 1-deep prefetch -> ~20 VGPR.
__global__ __launch_bounds__(256, 8)
void scores_kernel(const float* __restrict__ q2, const float* __restrict__ k2,
                   const float* __restrict__ scale, float* __restrict__ scores){
    __shared__ float qs[QB][UU];
    __shared__ float sc[UU];

    const int b   = blockIdx.z;
    const int q0  = blockIdx.x * QB;
    const int k0  = blockIdx.y * KR;
    const int tid = threadIdx.x;
    const int w   = tid >> 6, lane = tid & 63;

    #pragma unroll
    for (int i = 0; i < 2; ++i){
        int id = tid + 256*i;                   // 0..511
        qs[id >> 7][id & 127] = q2[((size_t)b * TQ + q0 + (id >> 7)) * UU + (id & 127)];
    }
    if (tid < UU) sc[tid] = -2.0f * scale[tid];
    __syncthreads();

    const float4* k2v = reinterpret_cast<const float4*>(k2 + (size_t)b * TV * UU);
    const float4* qs4 = reinterpret_cast<const float4*>(&qs[0][0]);   // row r: qs4[r*32 + j]
    const float4* sc4 = reinterpret_cast<const float4*>(&sc[0]);

    const int kA = k0 + w*64 + lane;            // the k this lane owns
    const size_t iA = (size_t)kA * 32;          // float4 index base

    float acc[QB] = {};
    float4 kva = k2v[iA];

    for (int j = 0; j < 32; ++j){
        float4 nka;
        if (j != 31) nka = k2v[iA + j + 1];
        float4 s4 = sc4[j];
        #pragma unroll
        for (int r = 0; r < QB; ++r){
            float4 q4 = qs4[r*32 + j];
            acc[r] = fmaf(s4.x, __builtin_amdgcn_rcpf(1.0f + __builtin_amdgcn_exp2f(q4.x + kva.x)), acc[r]);
            acc[r] = fmaf(s4.y, __builtin_amdgcn_rcpf(1.0f + __builtin_amdgcn_exp2f(q4.y + kva.y)), acc[r]);
            acc[r] = fmaf(s4.z, __builtin_amdgcn_rcpf(1.0f + __builtin_amdgcn_exp2f(q4.z + kva.z)), acc[r]);
            acc[r] = fmaf(s4.w, __builtin_amdgcn_rcpf(1.0f + __builtin_amdgcn_exp2f(q4.w + kva.w)), acc[r]);
        }
        kva = nka;
    }

    #pragma unroll
    for (int r = 0; r < QB; ++r)
        scores[((size_t)b * TQ + q0 + r) * TV + kA] = acc[r];
}

// ---------------- softmax over k (one wave per q-row) ----------------
__global__ __launch_bounds__(256)
void softmax_kernel(const float* __restrict__ scores, float* __restrict__ attn){
    const float LOG2E = 1.4426950408889634f;
    const int b = blockIdx.y, q = blockIdx.x * 4 + (threadIdx.x >> 6);
    const int lane = threadIdx.x & 63;
    const float* srow = scores + ((size_t)b * TQ + q) * TV;

    float s[16];
    #pragma unroll
    for (int t = 0; t < 16; ++t) s[t] = srow[t*64 + lane];

    float m = s[0];
    #pragma unroll
    for (int t = 1; t < 16; ++t) m = fmaxf(m, s[t]);
    #pragma unroll
    for (int off = 32; off >= 1; off >>= 1) m = fmaxf(m, __shfl_xor(m, off, 64));
    float sum = 0.f;
    #pragma unroll
    for (int t = 0; t < 16; ++t){ s[t] = __builtin_amdgcn_exp2f((s[t] - m) * LOG2E); sum += s[t]; }
    #pragma unroll
    for (int off = 32; off >= 1; off >>= 1) sum += __shfl_xor(sum, off, 64);
    float inv = 1.0f / sum;

    float* arow = attn + ((size_t)b * TQ + q) * TV;
    #pragma unroll
    for (int t = 0; t < 16; ++t) arow[t*64 + lane] = s[t] * inv;
}

// ---------------- context = attn @ value (all fp32) ----------------
__global__ __launch_bounds__(256)
void ctx_kernel(const float* __restrict__ attn, const float* __restrict__ value,
                float* __restrict__ ctx){
    __shared__ float As[CM][CKT + 4];
    __shared__ float Vs[CKT][CN];

    const int b  = blockIdx.z;
    const int m0 = blockIdx.x * CM;
    const int n0 = blockIdx.y * CN;
    const int tid = threadIdx.x;
    const int tx = tid & 15, ty = tid >> 4;

    const float* abase = attn + ((size_t)b * TQ + m0) * TV;
    const float* vbase = value + (size_t)b * TV * DD;

    float acc[2][4] = {};
    for (int kt = 0; kt < TV; kt += CKT){
        __syncthreads();
        #pragma unroll
        for (int i = 0; i < 2; ++i){
            int id = tid + 256*i;
            int row = id >> 4, c4 = id & 15;
            *reinterpret_cast<float4*>(&As[row][c4*4]) =
                *reinterpret_cast<const float4*>(abase + (size_t)row * TV + kt + c4*4);
        }
        #pragma unroll
        for (int i = 0; i < 4; ++i){
            int id = tid + 256*i;
            int row = id >> 4, c4 = id & 15;
            *reinterpret_cast<float4*>(&Vs[row][c4*4]) =
                *reinterpret_cast<const float4*>(vbase + (size_t)(kt + row) * DD + n0 + c4*4);
        }
        __syncthreads();
        #pragma unroll
        for (int k = 0; k < CKT; ++k){
            float a0 = As[ty*2+0][k];
            float a1 = As[ty*2+1][k];
            float4 b4 = *reinterpret_cast<const float4*>(&Vs[k][tx*4]);
            acc[0][0] = fmaf(a0, b4.x, acc[0][0]);
            acc[0][1] = fmaf(a0, b4.y, acc[0][1]);
            acc[0][2] = fmaf(a0, b4.z, acc[0][2]);
            acc[0][3] = fmaf(a0, b4.w, acc[0][3]);
            acc[1][0] = fmaf(a1, b4.x, acc[1][0]);
            acc[1][1] = fmaf(a1, b4.y, acc[1][1]);
            acc[1][2] = fmaf(a1, b4.z, acc[1][2]);
            acc[1][3] = fmaf(a1, b4.w, acc[1][3]);
        }
    }
    #pragma unroll
    for (int i = 0; i < 2; ++i){
        float4 o;
        o.x = acc[i][0]; o.y = acc[i][1]; o.z = acc[i][2]; o.w = acc[i][3];
        *reinterpret_cast<float4*>(ctx + ((size_t)b * TQ + m0 + ty*2 + i) * DD + n0 + tx*4) = o;
    }
}

extern "C" void kernel_launch(void* const* d_in, const int* in_sizes, int n_in,
                              void* d_out, int out_size, void* d_ws, size_t ws_size,
                              hipStream_t stream){
    const float* query = (const float*)d_in[0];
    const float* value = (const float*)d_in[1];
    const float* W1    = (const float*)d_in[2];
    const float* W2    = (const float*)d_in[3];
    const float* scale = (const float*)d_in[4];

    float* q2     = (float*)d_ws;                          // 1 MB
    float* k2     = q2 + (size_t)B_ * TQ * UU;             // 1 MB
    float* scores = k2 + (size_t)B_ * TV * UU;             // 8 MB raw scores

    float* out  = (float*)d_out;
    float* ctx  = out;                                     // [B][TQ][DD]
    float* attn = out + (size_t)B_ * TQ * DD;              // [B][TQ][TV]

    proj_kernel<<<dim3(TQ/8, B_, 2), 256, 0, stream>>>(query, value, W1, W2, q2, k2);
    scores_kernel<<<dim3(TQ/QB, KS, B_), 256, 0, stream>>>(q2, k2, scale, scores);
    softmax_kernel<<<dim3(TQ/4, B_), 256, 0, stream>>>(scores, attn);
    ctx_kernel<<<dim3(TQ/CM, DD/CN, B_), 256, 0, stream>>>(attn, value, ctx);
}

// Round 6
// 127.430 us; speedup vs baseline: 1.5675x; 1.1667x over previous
//
#include <hip/hip_runtime.h>

#define B_  2
#define TQ  1024
#define TV  1024
#define DD  512
#define UU  128

#define QB  4            // q-rows per block (scores)
#define KS  4            // k-splits (scores)
#define KR  (TV/KS)      // 256 k per block

#define CM  32
#define CN  64
#define CKT 64

// ---------------- projections + exp2 epilogue ----------------
// EQ = exp2(C*query@W1), EK = exp2(C*value@W2), C = 2*log2(e)
__global__ __launch_bounds__(256)
void proj_kernel(const float* __restrict__ query, const float* __restrict__ value,
                 const float* __restrict__ W1,    const float* __restrict__ W2,
                 float* __restrict__ eq, float* __restrict__ ek){
    const float TWO_LOG2E = 2.8853900817779268f;
    const float* X = blockIdx.z ? value : query;
    const float* W = blockIdx.z ? W2    : W1;
    float* out     = blockIdx.z ? ek    : eq;

    const int u    = threadIdx.x & 127;
    const int half = threadIdx.x >> 7;
    const int b    = blockIdx.y;
    const int t0   = blockIdx.x * 8 + half * 4;
    const float* x = X + ((size_t)b * TQ + t0) * DD;

    float acc0 = 0.f, acc1 = 0.f, acc2 = 0.f, acc3 = 0.f;
    for (int d = 0; d < DD; d += 4){
        float w0 = W[(d+0)*UU + u];
        float w1 = W[(d+1)*UU + u];
        float w2 = W[(d+2)*UU + u];
        float w3 = W[(d+3)*UU + u];
        float4 x0 = *reinterpret_cast<const float4*>(x + 0*DD + d);
        float4 x1 = *reinterpret_cast<const float4*>(x + 1*DD + d);
        float4 x2 = *reinterpret_cast<const float4*>(x + 2*DD + d);
        float4 x3 = *reinterpret_cast<const float4*>(x + 3*DD + d);
        acc0 = fmaf(x0.x,w0,acc0); acc0 = fmaf(x0.y,w1,acc0); acc0 = fmaf(x0.z,w2,acc0); acc0 = fmaf(x0.w,w3,acc0);
        acc1 = fmaf(x1.x,w0,acc1); acc1 = fmaf(x1.y,w1,acc1); acc1 = fmaf(x1.z,w2,acc1); acc1 = fmaf(x1.w,w3,acc1);
        acc2 = fmaf(x2.x,w0,acc2); acc2 = fmaf(x2.y,w1,acc2); acc2 = fmaf(x2.z,w2,acc2); acc2 = fmaf(x2.w,w3,acc2);
        acc3 = fmaf(x3.x,w0,acc3); acc3 = fmaf(x3.y,w1,acc3); acc3 = fmaf(x3.z,w2,acc3); acc3 = fmaf(x3.w,w3,acc3);
    }
    size_t o = ((size_t)b * TQ + t0) * UU + u;
    out[o + 0*UU] = __builtin_amdgcn_exp2f(TWO_LOG2E * acc0);
    out[o + 1*UU] = __builtin_amdgcn_exp2f(TWO_LOG2E * acc1);
    out[o + 2*UU] = __builtin_amdgcn_exp2f(TWO_LOG2E * acc2);
    out[o + 3*UU] = __builtin_amdgcn_exp2f(TWO_LOG2E * acc3);
}

// ---------------- raw scores ----------------
// scores[b,q,k] = sum_u (-2*scale[u]) * rcp(1 + EQ[b,q,u]*EK[b,k,u])  (+const, cancels in softmax)
// 2 VALU + 1 trans per element. block = 4 waves; wave w owns 64 k (1/lane), all 4 q-rows.
__global__ __launch_bounds__(256, 8)
void scores_kernel(const float* __restrict__ eq, const float* __restrict__ ek,
                   const float* __restrict__ scale, float* __restrict__ scores){
    __shared__ float qs[QB][UU];
    __shared__ float sc[UU];

    const int b   = blockIdx.z;
    const int q0  = blockIdx.x * QB;
    const int k0  = blockIdx.y * KR;
    const int tid = threadIdx.x;
    const int w   = tid >> 6, lane = tid & 63;

    #pragma unroll
    for (int i = 0; i < 2; ++i){
        int id = tid + 256*i;                   // 0..511
        qs[id >> 7][id & 127] = eq[((size_t)b * TQ + q0 + (id >> 7)) * UU + (id & 127)];
    }
    if (tid < UU) sc[tid] = -2.0f * scale[tid];
    __syncthreads();

    const float4* ekv = reinterpret_cast<const float4*>(ek + (size_t)b * TV * UU);
    const float4* qs4 = reinterpret_cast<const float4*>(&qs[0][0]);   // row r: qs4[r*32 + j]
    const float4* sc4 = reinterpret_cast<const float4*>(&sc[0]);

    const int kA = k0 + w*64 + lane;            // the k this lane owns
    const size_t iA = (size_t)kA * 32;          // float4 index base

    float acc[QB] = {};
    float4 kva = ekv[iA];

    for (int j = 0; j < 32; ++j){
        float4 nka;
        if (j != 31) nka = ekv[iA + j + 1];
        float4 s4 = sc4[j];
        #pragma unroll
        for (int r = 0; r < QB; ++r){
            float4 q4 = qs4[r*32 + j];
            acc[r] = fmaf(s4.x, __builtin_amdgcn_rcpf(fmaf(q4.x, kva.x, 1.0f)), acc[r]);
            acc[r] = fmaf(s4.y, __builtin_amdgcn_rcpf(fmaf(q4.y, kva.y, 1.0f)), acc[r]);
            acc[r] = fmaf(s4.z, __builtin_amdgcn_rcpf(fmaf(q4.z, kva.z, 1.0f)), acc[r]);
            acc[r] = fmaf(s4.w, __builtin_amdgcn_rcpf(fmaf(q4.w, kva.w, 1.0f)), acc[r]);
        }
        kva = nka;
    }

    #pragma unroll
    for (int r = 0; r < QB; ++r)
        scores[((size_t)b * TQ + q0 + r) * TV + kA] = acc[r];
}

// ---------------- softmax over k (one wave per q-row) ----------------
__global__ __launch_bounds__(256)
void softmax_kernel(const float* __restrict__ scores, float* __restrict__ attn){
    const float LOG2E = 1.4426950408889634f;
    const int b = blockIdx.y, q = blockIdx.x * 4 + (threadIdx.x >> 6);
    const int lane = threadIdx.x & 63;
    const float* srow = scores + ((size_t)b * TQ + q) * TV;

    float s[16];
    #pragma unroll
    for (int t = 0; t < 16; ++t) s[t] = srow[t*64 + lane];

    float m = s[0];
    #pragma unroll
    for (int t = 1; t < 16; ++t) m = fmaxf(m, s[t]);
    #pragma unroll
    for (int off = 32; off >= 1; off >>= 1) m = fmaxf(m, __shfl_xor(m, off, 64));
    float sum = 0.f;
    #pragma unroll
    for (int t = 0; t < 16; ++t){ s[t] = __builtin_amdgcn_exp2f((s[t] - m) * LOG2E); sum += s[t]; }
    #pragma unroll
    for (int off = 32; off >= 1; off >>= 1) sum += __shfl_xor(sum, off, 64);
    float inv = 1.0f / sum;

    float* arow = attn + ((size_t)b * TQ + q) * TV;
    #pragma unroll
    for (int t = 0; t < 16; ++t) arow[t*64 + lane] = s[t] * inv;
}

// ---------------- context = attn @ value (fp32, k-step-4 b128 inner loop) ----
__global__ __launch_bounds__(256)
void ctx_kernel(const float* __restrict__ attn, const float* __restrict__ value,
                float* __restrict__ ctx){
    __shared__ float As[CM][CKT + 4];   // row stride 68 floats = 272 B (16B-multiple)
    __shared__ float Vs[CKT][CN];

    const int b  = blockIdx.z;
    const int m0 = blockIdx.x * CM;
    const int n0 = blockIdx.y * CN;
    const int tid = threadIdx.x;
    const int tx = tid & 15, ty = tid >> 4;

    const float* abase = attn + ((size_t)b * TQ + m0) * TV;
    const float* vbase = value + (size_t)b * TV * DD;

    float acc[2][4] = {};
    for (int kt = 0; kt < TV; kt += CKT){
        __syncthreads();
        #pragma unroll
        for (int i = 0; i < 2; ++i){
            int id = tid + 256*i;
            int row = id >> 4, c4 = id & 15;
            *reinterpret_cast<float4*>(&As[row][c4*4]) =
                *reinterpret_cast<const float4*>(abase + (size_t)row * TV + kt + c4*4);
        }
        #pragma unroll
        for (int i = 0; i < 4; ++i){
            int id = tid + 256*i;
            int row = id >> 4, c4 = id & 15;
            *reinterpret_cast<float4*>(&Vs[row][c4*4]) =
                *reinterpret_cast<const float4*>(vbase + (size_t)(kt + row) * DD + n0 + c4*4);
        }
        __syncthreads();
        #pragma unroll 4
        for (int k = 0; k < CKT; k += 4){
            float4 a0 = *reinterpret_cast<const float4*>(&As[ty*2+0][k]);
            float4 a1 = *reinterpret_cast<const float4*>(&As[ty*2+1][k]);
            float4 v0 = *reinterpret_cast<const float4*>(&Vs[k+0][tx*4]);
            float4 v1 = *reinterpret_cast<const float4*>(&Vs[k+1][tx*4]);
            float4 v2 = *reinterpret_cast<const float4*>(&Vs[k+2][tx*4]);
            float4 v3 = *reinterpret_cast<const float4*>(&Vs[k+3][tx*4]);

            acc[0][0] = fmaf(a0.x, v0.x, acc[0][0]); acc[0][1] = fmaf(a0.x, v0.y, acc[0][1]);
            acc[0][2] = fmaf(a0.x, v0.z, acc[0][2]); acc[0][3] = fmaf(a0.x, v0.w, acc[0][3]);
            acc[1][0] = fmaf(a1.x, v0.x, acc[1][0]); acc[1][1] = fmaf(a1.x, v0.y, acc[1][1]);
            acc[1][2] = fmaf(a1.x, v0.z, acc[1][2]); acc[1][3] = fmaf(a1.x, v0.w, acc[1][3]);

            acc[0][0] = fmaf(a0.y, v1.x, acc[0][0]); acc[0][1] = fmaf(a0.y, v1.y, acc[0][1]);
            acc[0][2] = fmaf(a0.y, v1.z, acc[0][2]); acc[0][3] = fmaf(a0.y, v1.w, acc[0][3]);
            acc[1][0] = fmaf(a1.y, v1.x, acc[1][0]); acc[1][1] = fmaf(a1.y, v1.y, acc[1][1]);
            acc[1][2] = fmaf(a1.y, v1.z, acc[1][2]); acc[1][3] = fmaf(a1.y, v1.w, acc[1][3]);

            acc[0][0] = fmaf(a0.z, v2.x, acc[0][0]); acc[0][1] = fmaf(a0.z, v2.y, acc[0][1]);
            acc[0][2] = fmaf(a0.z, v2.z, acc[0][2]); acc[0][3] = fmaf(a0.z, v2.w, acc[0][3]);
            acc[1][0] = fmaf(a1.z, v2.x, acc[1][0]); acc[1][1] = fmaf(a1.z, v2.y, acc[1][1]);
            acc[1][2] = fmaf(a1.z, v2.z, acc[1][2]); acc[1][3] = fmaf(a1.z, v2.w, acc[1][3]);

            acc[0][0] = fmaf(a0.w, v3.x, acc[0][0]); acc[0][1] = fmaf(a0.w, v3.y, acc[0][1]);
            acc[0][2] = fmaf(a0.w, v3.z, acc[0][2]); acc[0][3] = fmaf(a0.w, v3.w, acc[0][3]);
            acc[1][0] = fmaf(a1.w, v3.x, acc[1][0]); acc[1][1] = fmaf(a1.w, v3.y, acc[1][1]);
            acc[1][2] = fmaf(a1.w, v3.z, acc[1][2]); acc[1][3] = fmaf(a1.w, v3.w, acc[1][3]);
        }
    }
    #pragma unroll
    for (int i = 0; i < 2; ++i){
        float4 o;
        o.x = acc[i][0]; o.y = acc[i][1]; o.z = acc[i][2]; o.w = acc[i][3];
        *reinterpret_cast<float4*>(ctx + ((size_t)b * TQ + m0 + ty*2 + i) * DD + n0 + tx*4) = o;
    }
}

extern "C" void kernel_launch(void* const* d_in, const int* in_sizes, int n_in,
                              void* d_out, int out_size, void* d_ws, size_t ws_size,
                              hipStream_t stream){
    const float* query = (const float*)d_in[0];
    const float* value = (const float*)d_in[1];
    const float* W1    = (const float*)d_in[2];
    const float* W2    = (const float*)d_in[3];
    const float* scale = (const float*)d_in[4];

    float* eq     = (float*)d_ws;                          // 1 MB
    float* ek     = eq + (size_t)B_ * TQ * UU;             // 1 MB
    float* scores = ek + (size_t)B_ * TV * UU;             // 8 MB raw scores

    float* out  = (float*)d_out;
    float* ctx  = out;                                     // [B][TQ][DD]
    float* attn = out + (size_t)B_ * TQ * DD;              // [B][TQ][TV]

    proj_kernel<<<dim3(TQ/8, B_, 2), 256, 0, stream>>>(query, value, W1, W2, eq, ek);
    scores_kernel<<<dim3(TQ/QB, KS, B_), 256, 0, stream>>>(eq, ek, scale, scores);
    softmax_kernel<<<dim3(TQ/4, B_), 256, 0, stream>>>(scores, attn);
    ctx_kernel<<<dim3(TQ/CM, DD/CN, B_), 256, 0, stream>>>(attn, value, ctx);
}

// Round 7
// 110.463 us; speedup vs baseline: 1.8082x; 1.1536x over previous
//
#include <hip/hip_runtime.h>

#define B_  2
#define TQ  1024
#define TV  1024
#define DD  512
#define UU  128

#define QB  4            // q-rows per block (scores)
#define KS  4            // k-splits (scores)
#define KR  (TV/KS)      // 256 k per block

typedef __attribute__((ext_vector_type(8))) short short8;
typedef __attribute__((ext_vector_type(4))) float f32x4;

__device__ __forceinline__ unsigned short f2bf(float x){
    unsigned int u = __float_as_uint(x);
    unsigned int r = (u + 0x7FFFu + ((u >> 16) & 1u)) >> 16;
    return (unsigned short)r;
}
__device__ __forceinline__ float bf2f(unsigned short h){
    return __uint_as_float(((unsigned int)h) << 16);
}

// ---------------- projections + exp2 epilogue ----------------
// EQ = exp2(C*query@W1), EK = exp2(C*value@W2), C = 2*log2(e)
__global__ __launch_bounds__(256)
void proj_kernel(const float* __restrict__ query, const float* __restrict__ value,
                 const float* __restrict__ W1,    const float* __restrict__ W2,
                 float* __restrict__ eq, float* __restrict__ ek){
    const float TWO_LOG2E = 2.8853900817779268f;
    const float* X = blockIdx.z ? value : query;
    const float* W = blockIdx.z ? W2    : W1;
    float* out     = blockIdx.z ? ek    : eq;

    const int u    = threadIdx.x & 127;
    const int half = threadIdx.x >> 7;
    const int b    = blockIdx.y;
    const int t0   = blockIdx.x * 8 + half * 4;
    const float* x = X + ((size_t)b * TQ + t0) * DD;

    float acc0 = 0.f, acc1 = 0.f, acc2 = 0.f, acc3 = 0.f;
    for (int d = 0; d < DD; d += 4){
        float w0 = W[(d+0)*UU + u];
        float w1 = W[(d+1)*UU + u];
        float w2 = W[(d+2)*UU + u];
        float w3 = W[(d+3)*UU + u];
        float4 x0 = *reinterpret_cast<const float4*>(x + 0*DD + d);
        float4 x1 = *reinterpret_cast<const float4*>(x + 1*DD + d);
        float4 x2 = *reinterpret_cast<const float4*>(x + 2*DD + d);
        float4 x3 = *reinterpret_cast<const float4*>(x + 3*DD + d);
        acc0 = fmaf(x0.x,w0,acc0); acc0 = fmaf(x0.y,w1,acc0); acc0 = fmaf(x0.z,w2,acc0); acc0 = fmaf(x0.w,w3,acc0);
        acc1 = fmaf(x1.x,w0,acc1); acc1 = fmaf(x1.y,w1,acc1); acc1 = fmaf(x1.z,w2,acc1); acc1 = fmaf(x1.w,w3,acc1);
        acc2 = fmaf(x2.x,w0,acc2); acc2 = fmaf(x2.y,w1,acc2); acc2 = fmaf(x2.z,w2,acc2); acc2 = fmaf(x2.w,w3,acc2);
        acc3 = fmaf(x3.x,w0,acc3); acc3 = fmaf(x3.y,w1,acc3); acc3 = fmaf(x3.z,w2,acc3); acc3 = fmaf(x3.w,w3,acc3);
    }
    size_t o = ((size_t)b * TQ + t0) * UU + u;
    out[o + 0*UU] = __builtin_amdgcn_exp2f(TWO_LOG2E * acc0);
    out[o + 1*UU] = __builtin_amdgcn_exp2f(TWO_LOG2E * acc1);
    out[o + 2*UU] = __builtin_amdgcn_exp2f(TWO_LOG2E * acc2);
    out[o + 3*UU] = __builtin_amdgcn_exp2f(TWO_LOG2E * acc3);
}

// ---------------- raw scores ----------------
// scores[b,q,k] = sum_u (-2*scale[u]) * rcp(1 + EQ[b,q,u]*EK[b,k,u])  (+const, cancels in softmax)
__global__ __launch_bounds__(256, 8)
void scores_kernel(const float* __restrict__ eq, const float* __restrict__ ek,
                   const float* __restrict__ scale, float* __restrict__ scores){
    __shared__ float qs[QB][UU];
    __shared__ float sc[UU];

    const int b   = blockIdx.z;
    const int q0  = blockIdx.x * QB;
    const int k0  = blockIdx.y * KR;
    const int tid = threadIdx.x;
    const int w   = tid >> 6, lane = tid & 63;

    #pragma unroll
    for (int i = 0; i < 2; ++i){
        int id = tid + 256*i;                   // 0..511
        qs[id >> 7][id & 127] = eq[((size_t)b * TQ + q0 + (id >> 7)) * UU + (id & 127)];
    }
    if (tid < UU) sc[tid] = -2.0f * scale[tid];
    __syncthreads();

    const float4* ekv = reinterpret_cast<const float4*>(ek + (size_t)b * TV * UU);
    const float4* qs4 = reinterpret_cast<const float4*>(&qs[0][0]);   // row r: qs4[r*32 + j]
    const float4* sc4 = reinterpret_cast<const float4*>(&sc[0]);

    const int kA = k0 + w*64 + lane;            // the k this lane owns
    const size_t iA = (size_t)kA * 32;          // float4 index base

    float acc[QB] = {};
    float4 kva = ekv[iA];

    for (int j = 0; j < 32; ++j){
        float4 nka;
        if (j != 31) nka = ekv[iA + j + 1];
        float4 s4 = sc4[j];
        #pragma unroll
        for (int r = 0; r < QB; ++r){
            float4 q4 = qs4[r*32 + j];
            acc[r] = fmaf(s4.x, __builtin_amdgcn_rcpf(fmaf(q4.x, kva.x, 1.0f)), acc[r]);
            acc[r] = fmaf(s4.y, __builtin_amdgcn_rcpf(fmaf(q4.y, kva.y, 1.0f)), acc[r]);
            acc[r] = fmaf(s4.z, __builtin_amdgcn_rcpf(fmaf(q4.z, kva.z, 1.0f)), acc[r]);
            acc[r] = fmaf(s4.w, __builtin_amdgcn_rcpf(fmaf(q4.w, kva.w, 1.0f)), acc[r]);
        }
        kva = nka;
    }

    #pragma unroll
    for (int r = 0; r < QB; ++r)
        scores[((size_t)b * TQ + q0 + r) * TV + kA] = acc[r];
}

// ---------------- softmax over k (one wave per q-row) ----------------
__global__ __launch_bounds__(256)
void softmax_kernel(const float* __restrict__ scores, float* __restrict__ attn){
    const float LOG2E = 1.4426950408889634f;
    const int b = blockIdx.y, q = blockIdx.x * 4 + (threadIdx.x >> 6);
    const int lane = threadIdx.x & 63;
    const float* srow = scores + ((size_t)b * TQ + q) * TV;

    float s[16];
    #pragma unroll
    for (int t = 0; t < 16; ++t) s[t] = srow[t*64 + lane];

    float m = s[0];
    #pragma unroll
    for (int t = 1; t < 16; ++t) m = fmaxf(m, s[t]);
    #pragma unroll
    for (int off = 32; off >= 1; off >>= 1) m = fmaxf(m, __shfl_xor(m, off, 64));
    float sum = 0.f;
    #pragma unroll
    for (int t = 0; t < 16; ++t){ s[t] = __builtin_amdgcn_exp2f((s[t] - m) * LOG2E); sum += s[t]; }
    #pragma unroll
    for (int off = 32; off >= 1; off >>= 1) sum += __shfl_xor(sum, off, 64);
    float inv = 1.0f / sum;

    float* arow = attn + ((size_t)b * TQ + q) * TV;
    #pragma unroll
    for (int t = 0; t < 16; ++t) arow[t*64 + lane] = s[t] * inv;
}

// ---------------- context = attn @ value via bf16-split MFMA ----------------
// ctx = (ah+al)@(vh+vl) ~= ah@vh + al@vh + ah@vl  (fp32 MFMA accum)
// error <= ~3*2^-18 * max|v| ~ 6e-5 since sum_k attn = 1.
// Tile 64x64, K-step 64, 4 waves (2x2), 16x16x32 MFMA, k-group XOR swizzle.
__global__ __launch_bounds__(256)
void ctx_kernel(const float* __restrict__ attn, const float* __restrict__ value,
                float* __restrict__ ctx){
    __shared__ unsigned short Ah[64*64], Al[64*64], Vh[64*64], Vl[64*64];

    const int m0   = blockIdx.x * 64;        // global row in [0, B*TQ)
    const int n0   = blockIdx.y * 64;
    const int b    = m0 >> 10;
    const int tid  = threadIdx.x;
    const int lane = tid & 63;
    const int w    = tid >> 6;
    const int wm   = w >> 1, wn = w & 1;

    // staging ownership: row/col = tid>>2, k-chunk of 16 = (tid&3)*16
    const int am = tid >> 2;
    const int kq = (tid & 3) * 16;

    const float* arow  = attn  + (size_t)(m0 + am) * TV;
    const float* vbase = value + (size_t)b * TV * DD + n0 + am;

    float ra[16];
    float rv[16];
    #pragma unroll
    for (int i = 0; i < 4; ++i)
        *reinterpret_cast<float4*>(&ra[i*4]) = *reinterpret_cast<const float4*>(arow + kq + i*4);
    #pragma unroll
    for (int e = 0; e < 16; ++e) rv[e] = vbase[(size_t)(kq + e) * DD];

    f32x4 acc[2][2];
    #pragma unroll
    for (int i = 0; i < 2; ++i)
        #pragma unroll
        for (int j = 0; j < 2; ++j)
            acc[i][j] = (f32x4){0.f, 0.f, 0.f, 0.f};

    for (int kt = 0; kt < TV; kt += 64){
        // ---- convert + stage current tile from regs ----
        #pragma unroll
        for (int gg = 0; gg < 2; ++gg){
            unsigned short h8[8], l8[8], vh8[8], vl8[8];
            #pragma unroll
            for (int e = 0; e < 8; ++e){
                float a = ra[gg*8 + e];
                unsigned short h = f2bf(a);
                h8[e] = h; l8[e] = f2bf(a - bf2f(h));
                float v = rv[gg*8 + e];
                unsigned short vh = f2bf(v);
                vh8[e] = vh; vl8[e] = f2bf(v - bf2f(vh));
            }
            int g = ((kq >> 3) + gg) ^ (am & 7);
            *reinterpret_cast<int4*>(&Ah[am*64 + g*8]) = *reinterpret_cast<const int4*>(h8);
            *reinterpret_cast<int4*>(&Al[am*64 + g*8]) = *reinterpret_cast<const int4*>(l8);
            *reinterpret_cast<int4*>(&Vh[am*64 + g*8]) = *reinterpret_cast<const int4*>(vh8);
            *reinterpret_cast<int4*>(&Vl[am*64 + g*8]) = *reinterpret_cast<const int4*>(vl8);
        }

        // ---- prefetch next tile into regs (in flight across compute) ----
        const int ktn = (kt + 64 < TV) ? kt + 64 : 0;
        #pragma unroll
        for (int i = 0; i < 4; ++i)
            *reinterpret_cast<float4*>(&ra[i*4]) = *reinterpret_cast<const float4*>(arow + ktn + kq + i*4);
        #pragma unroll
        for (int e = 0; e < 16; ++e) rv[e] = vbase[(size_t)(ktn + kq + e) * DD];

        __syncthreads();

        // ---- MFMA on staged tile ----
        #pragma unroll
        for (int kk = 0; kk < 2; ++kk){
            const int kg = kk*4 + (lane >> 4);
            const int g  = (kg ^ (lane & 7)) * 8;
            const int r0 = (wm*32 + (lane & 15)) * 64;
            const int c0 = (wn*32 + (lane & 15)) * 64;

            short8 a0h = *reinterpret_cast<const short8*>(&Ah[r0 + g]);
            short8 a1h = *reinterpret_cast<const short8*>(&Ah[r0 + 16*64 + g]);
            short8 a0l = *reinterpret_cast<const short8*>(&Al[r0 + g]);
            short8 a1l = *reinterpret_cast<const short8*>(&Al[r0 + 16*64 + g]);
            short8 b0h = *reinterpret_cast<const short8*>(&Vh[c0 + g]);
            short8 b1h = *reinterpret_cast<const short8*>(&Vh[c0 + 16*64 + g]);
            short8 b0l = *reinterpret_cast<const short8*>(&Vl[c0 + g]);
            short8 b1l = *reinterpret_cast<const short8*>(&Vl[c0 + 16*64 + g]);

            acc[0][0] = __builtin_amdgcn_mfma_f32_16x16x32_bf16(a0h, b0h, acc[0][0], 0, 0, 0);
            acc[0][0] = __builtin_amdgcn_mfma_f32_16x16x32_bf16(a0l, b0h, acc[0][0], 0, 0, 0);
            acc[0][0] = __builtin_amdgcn_mfma_f32_16x16x32_bf16(a0h, b0l, acc[0][0], 0, 0, 0);

            acc[0][1] = __builtin_amdgcn_mfma_f32_16x16x32_bf16(a0h, b1h, acc[0][1], 0, 0, 0);
            acc[0][1] = __builtin_amdgcn_mfma_f32_16x16x32_bf16(a0l, b1h, acc[0][1], 0, 0, 0);
            acc[0][1] = __builtin_amdgcn_mfma_f32_16x16x32_bf16(a0h, b1l, acc[0][1], 0, 0, 0);

            acc[1][0] = __builtin_amdgcn_mfma_f32_16x16x32_bf16(a1h, b0h, acc[1][0], 0, 0, 0);
            acc[1][0] = __builtin_amdgcn_mfma_f32_16x16x32_bf16(a1l, b0h, acc[1][0], 0, 0, 0);
            acc[1][0] = __builtin_amdgcn_mfma_f32_16x16x32_bf16(a1h, b0l, acc[1][0], 0, 0, 0);

            acc[1][1] = __builtin_amdgcn_mfma_f32_16x16x32_bf16(a1h, b1h, acc[1][1], 0, 0, 0);
            acc[1][1] = __builtin_amdgcn_mfma_f32_16x16x32_bf16(a1l, b1h, acc[1][1], 0, 0, 0);
            acc[1][1] = __builtin_amdgcn_mfma_f32_16x16x32_bf16(a1h, b1l, acc[1][1], 0, 0, 0);
        }

        __syncthreads();
    }

    // ---- epilogue: C/D layout col = lane&15, row = (lane>>4)*4 + reg ----
    #pragma unroll
    for (int fm = 0; fm < 2; ++fm){
        #pragma unroll
        for (int fn = 0; fn < 2; ++fn){
            const int row = m0 + wm*32 + fm*16 + (lane >> 4) * 4;
            const int col = n0 + wn*32 + fn*16 + (lane & 15);
            #pragma unroll
            for (int r = 0; r < 4; ++r)
                ctx[(size_t)(row + r) * DD + col] = acc[fm][fn][r];
        }
    }
}

extern "C" void kernel_launch(void* const* d_in, const int* in_sizes, int n_in,
                              void* d_out, int out_size, void* d_ws, size_t ws_size,
                              hipStream_t stream){
    const float* query = (const float*)d_in[0];
    const float* value = (const float*)d_in[1];
    const float* W1    = (const float*)d_in[2];
    const float* W2    = (const float*)d_in[3];
    const float* scale = (const float*)d_in[4];

    float* eq     = (float*)d_ws;                          // 1 MB
    float* ek     = eq + (size_t)B_ * TQ * UU;             // 1 MB
    float* scores = ek + (size_t)B_ * TV * UU;             // 8 MB raw scores

    float* out  = (float*)d_out;
    float* ctx  = out;                                     // [B][TQ][DD]
    float* attn = out + (size_t)B_ * TQ * DD;              // [B][TQ][TV]

    proj_kernel<<<dim3(TQ/8, B_, 2), 256, 0, stream>>>(query, value, W1, W2, eq, ek);
    scores_kernel<<<dim3(TQ/QB, KS, B_), 256, 0, stream>>>(eq, ek, scale, scores);
    softmax_kernel<<<dim3(TQ/4, B_), 256, 0, stream>>>(scores, attn);
    ctx_kernel<<<dim3((B_*TQ)/64, DD/64), 256, 0, stream>>>(attn, value, ctx);
}